// Round 14
// baseline (1922.055 us; speedup 1.0000x reference)
//
#include <hip/hip_runtime.h>
#include <hip/hip_bf16.h>
#include <math.h>

#define N_NODES 100000
#define N_PAD   100096   // multiple of 256
#define N_EDGES 400000
#define IN_DIM  100
#define D       200
#define DP      208      // j padded to 13*16
#define KP      224      // k padded to 7*32
#define NUM_STEPS 4

#define TILE_SHORTS  21504         // full jt tile: 6 gates * 7 kt * 64 lanes * 8 shorts
#define STAGE_SHORTS 7168          // 2-gate stage: 14336 B
#define STAGE_GROUPS 14            // 14336 B / (64 lanes * 16 B)
#define EIDX_CAP     512           // per-wave LDS edge-index capacity

typedef __attribute__((ext_vector_type(8))) short bfrag;   // 8 bf16 (4 VGPRs)
typedef __attribute__((ext_vector_type(4))) float facc;    // 4 fp32

// Wc[s] = w_ih @ W[s]^T so that gi = aggr_raw @ Wc[s]^T  (scatter is linear)
__device__ float g_Wc[NUM_STEPS * 600 * D];
// weights, per-(step,jt) CONTIGUOUS tile: [s][jt][g6][t7][lane64][8]
__device__ short g_Wall[NUM_STEPS * 13 * TILE_SHORTS];
__device__ float g_bias[6 * DP];

__device__ __forceinline__ float fast_sigmoid(float x) {
    return __builtin_amdgcn_rcpf(1.0f + __expf(-x));
}
__device__ __forceinline__ float fast_tanh(float x) {
    return 2.0f * __builtin_amdgcn_rcpf(1.0f + __expf(-2.0f * x)) - 1.0f;
}
__device__ __forceinline__ float bf2f(short u) {
    unsigned int x = ((unsigned int)(unsigned short)u) << 16;
    return __uint_as_float(x);
}

// ---------------- Wc precompute: block=(s*600+j), thread=k ----------------
__global__ __launch_bounds__(256) void wc_kernel(const float* __restrict__ W,
                                                 const float* __restrict__ w_ih) {
    int s = blockIdx.x / 600;
    int j = blockIdx.x % 600;
    int k = threadIdx.x;
    if (k >= D) return;
    const float* wr = &w_ih[(size_t)j * D];
    const float* Wr = &W[(size_t)s * D * D + (size_t)k * D];
    float acc = 0.0f;
    #pragma unroll 4
    for (int t = 0; t < D; ++t) acc += wr[t] * Wr[t];
    g_Wc[((size_t)s * 600 + j) * D + k] = acc;
}

// ---------------- permute weights into per-tile fragment order + bias prep ----------------
__global__ __launch_bounds__(256) void wconv_kernel(const float* __restrict__ w_hh,
                                                    const float* __restrict__ b_ih,
                                                    const float* __restrict__ b_hh) {
    if (blockIdx.x >= 546) {
        int idx = (blockIdx.x - 546) * 256 + threadIdx.x;
        if (idx < 6 * DP) {
            int g = idx / DP, j = idx % DP;
            float v = 0.0f;
            if (j < D) v = (g < 3) ? b_ih[g * 200 + j] : b_hh[(g - 3) * 200 + j];
            g_bias[idx] = v;
        }
        return;
    }
    int idx = blockIdx.x * 256 + threadIdx.x;   // < 4*13*6*7*64 = 139776
    int l  = idx & 63;
    int t  = (idx >> 6) % 7;
    int g  = (idx / 448) % 6;
    int jt = (idx / 2688) % 13;
    int s  = idx / 34944;
    int j  = jt * 16 + (l & 15);
    int k0 = t * 32 + (l >> 4) * 8;
    short* out = g_Wall + (size_t)idx * 8;
    #pragma unroll
    for (int i = 0; i < 8; ++i) {
        int k = k0 + i;
        float v = 0.0f;
        if (j < D && k < D)
            v = (g < 3) ? g_Wc[((size_t)s * 600 + g * 200 + j) * D + k]
                        : w_hh[((size_t)(g - 3) * 200 + j) * D + k];
        __hip_bfloat16 b = __float2bfloat16(v);
        out[i] = *reinterpret_cast<short*>(&b);
    }
}

// ---------------- pad: h[:, :100] = bf16(x), rest 0 ----------------
__global__ void pad_kernel(const float* __restrict__ x, __hip_bfloat16* __restrict__ h) {
    int idx = blockIdx.x * 256 + threadIdx.x;   // N_PAD*KP exact multiple of 256
    int n = idx / KP, c = idx % KP;
    float v = (n < N_NODES && c < IN_DIM) ? x[n * IN_DIM + c] : 0.0f;
    h[idx] = __float2bfloat16(v);
}

// ---------------- CSR build ----------------
__global__ void count_kernel(const int* __restrict__ dst, int* __restrict__ cnt) {
    int e = blockIdx.x * blockDim.x + threadIdx.x;
    if (e < N_EDGES) atomicAdd(&cnt[dst[e]], 1);
}

#define SCAN_B 1024
// 2-barrier block scan: wave shuffle-scan + cross-wave LDS
__global__ __launch_bounds__(SCAN_B) void scan1(const int* __restrict__ cnt,
                                                int* __restrict__ incl, int* __restrict__ bsum) {
    __shared__ int ws[16];
    int i = blockIdx.x * SCAN_B + threadIdx.x;
    int lane = threadIdx.x & 63, wid = threadIdx.x >> 6;
    int v = (i < N_NODES) ? cnt[i] : 0;
    int s = v;
    #pragma unroll
    for (int o = 1; o < 64; o <<= 1) {
        int t = __shfl_up(s, o, 64);
        if (lane >= o) s += t;
    }
    if (lane == 63) ws[wid] = s;
    __syncthreads();
    if (wid == 0) {
        int t = (lane < 16) ? ws[lane] : 0;
        #pragma unroll
        for (int o = 1; o < 16; o <<= 1) {
            int u = __shfl_up(t, o, 64);
            if (lane >= o) t += u;
        }
        if (lane < 16) ws[lane] = t;
    }
    __syncthreads();
    if (wid > 0) s += ws[wid - 1];
    if (i < N_NODES) incl[i] = s;
    if (threadIdx.x == SCAN_B - 1) bsum[blockIdx.x] = s;
}
__global__ void scan2(int* __restrict__ bsum, int nb) {
    __shared__ int sh[128];
    int v = (threadIdx.x < nb) ? bsum[threadIdx.x] : 0;
    sh[threadIdx.x] = v; __syncthreads();
    for (int off = 1; off < 128; off <<= 1) {
        int t = (threadIdx.x >= off) ? sh[threadIdx.x - off] : 0;
        __syncthreads();
        sh[threadIdx.x] += t;
        __syncthreads();
    }
    if (threadIdx.x < nb) bsum[threadIdx.x] = sh[threadIdx.x] - v;  // exclusive
}
__global__ void scan3(const int* __restrict__ cnt, const int* __restrict__ incl,
                      const int* __restrict__ bsum, int* __restrict__ off,
                      int* __restrict__ cursor) {
    int i = blockIdx.x * blockDim.x + threadIdx.x;
    if (i < N_NODES) {
        int v = incl[i] - cnt[i] + bsum[i / SCAN_B];
        off[i] = v; cursor[i] = v;
    }
    if (i == 0) off[N_NODES] = N_EDGES;
}
__global__ void fill_kernel(const int* __restrict__ src, const int* __restrict__ dst,
                            int* __restrict__ cursor, int* __restrict__ esrc) {
    int e = blockIdx.x * blockDim.x + threadIdx.x;
    if (e < N_EDGES) {
        int pos = atomicAdd(&cursor[dst[e]], 1);
        esrc[pos] = src[e];
    }
}

// ---------------- async stage: one 2-gate stage (14336 B) global -> LDS ----------------
__device__ __forceinline__ void stage_third(const short* __restrict__ gsrc,
                                            short* lds_dst, int wave, int lane) {
    #pragma unroll
    for (int g = wave; g < STAGE_GROUPS; g += 4) {
        __builtin_amdgcn_global_load_lds(
            (const __attribute__((address_space(1))) void*)(gsrc + g * 512 + lane * 8),
            (__attribute__((address_space(3))) void*)(lds_dst + g * 512),
            16, 0, 0);
    }
}

// ---------------- fused gather + MFMA GRU (+ pool on last step) ----------------
// grid N_PAD/128 = 782 blocks; LDS ~37.7 KB + __launch_bounds__(256,4) targets
// 4 blocks/CU -> all 782 blocks in ONE generation (no 14-block tail).
// Gather (r11 scheme): per-wave esrc slice in LDS, 4 rows in flight, 4-edge unroll.
// MFMA: 39 2-gate stages, double-buffered global_load_lds DMA (2 x 14336 B buffers
// exactly aliasing the 28672 B gather scratch).
__global__ __launch_bounds__(256, 4) void gru_fused(const __hip_bfloat16* __restrict__ hcur,
                                                    __hip_bfloat16* __restrict__ hnext,
                                                    const int* __restrict__ off,
                                                    const int* __restrict__ esrc,
                                                    unsigned int* __restrict__ pooled,
                                                    int step) {
    __shared__ short LDS[2 * STAGE_SHORTS];   // 28672 B: gather scratch / 2 stage bufs
    __shared__ int eidx_s[4 * EIDX_CAP];      // 8192 B edge-index cache
    __shared__ unsigned int pmax[DP];         // step-3 pooling scratch
    int tid = threadIdx.x;
    int lane = tid & 63, wave = tid >> 6;
    int wbase = blockIdx.x * 128 + wave * 32;
    int mrow = lane & 15, kq = lane >> 4;
    bool dopool = (step == NUM_STEPS - 1);

    if (dopool) for (int c = tid; c < DP; c += 256) pmax[c] = 0u;

    short* Awave = LDS + wave * 16 * KP;        // 16 rows x 224 shorts per wave
    int* EIdx = eidx_s + wave * EIDX_CAP;

    // ---- prefetch this wave's contiguous esrc slice (CSR rows are contiguous) ----
    int nlo = wbase < N_NODES ? wbase : N_NODES;
    int nhi = (wbase + 32) < N_NODES ? (wbase + 32) : N_NODES;
    int lo = off[nlo];
    int cntw = off[nhi] - lo;
    bool use_lds = (cntw <= EIDX_CAP);
    if (use_lds)
        for (int i = lane; i < cntw; i += 64) EIdx[i] = esrc[lo + i];

    bfrag av[2][7], hv[2][7];

    // ---- gather: 2 phases x 16 rows; 4 rows in flight, 4-edge unroll ----
    int r4 = lane >> 4;              // row-in-flight 0..3
    int ck = lane & 15;              // 16B chunk id (this lane also covers ck+16)
    int colA = ck * 8;
    int colB = colA + 128;           // (ck+16)*8
    bool sumB = (ck < 9);            // chunks 16..24 carry data (cols < 200)
    #pragma unroll
    for (int p = 0; p < 2; ++p) {
        #pragma unroll
        for (int it = 0; it < 4; ++it) {
            int rr = it * 4 + r4;            // row within phase
            int n = wbase + p * 16 + rr;
            float a[8] = {0, 0, 0, 0, 0, 0, 0, 0};
            float b[8] = {0, 0, 0, 0, 0, 0, 0, 0};
            if (n < N_NODES) {
                int e0 = off[n] - lo, e1 = off[n + 1] - lo;
                int e = e0;
                for (; e + 3 < e1; e += 4) {
                    int i0, i1, i2, i3;
                    if (use_lds) {
                        i0 = EIdx[e]; i1 = EIdx[e + 1]; i2 = EIdx[e + 2]; i3 = EIdx[e + 3];
                    } else {
                        i0 = esrc[lo + e];     i1 = esrc[lo + e + 1];
                        i2 = esrc[lo + e + 2]; i3 = esrc[lo + e + 3];
                    }
                    size_t s0 = (size_t)i0 * KP, s1 = (size_t)i1 * KP;
                    size_t s2 = (size_t)i2 * KP, s3 = (size_t)i3 * KP;
                    bfrag a0 = *(const bfrag*)(hcur + s0 + colA);
                    bfrag a1 = *(const bfrag*)(hcur + s1 + colA);
                    bfrag a2 = *(const bfrag*)(hcur + s2 + colA);
                    bfrag a3 = *(const bfrag*)(hcur + s3 + colA);
                    if (sumB) {
                        bfrag b0 = *(const bfrag*)(hcur + s0 + colB);
                        bfrag b1 = *(const bfrag*)(hcur + s1 + colB);
                        bfrag b2 = *(const bfrag*)(hcur + s2 + colB);
                        bfrag b3 = *(const bfrag*)(hcur + s3 + colB);
                        #pragma unroll
                        for (int q = 0; q < 8; ++q)
                            b[q] += (bf2f(b0[q]) + bf2f(b1[q])) + (bf2f(b2[q]) + bf2f(b3[q]));
                    }
                    #pragma unroll
                    for (int q = 0; q < 8; ++q)
                        a[q] += (bf2f(a0[q]) + bf2f(a1[q])) + (bf2f(a2[q]) + bf2f(a3[q]));
                }
                for (; e < e1; ++e) {
                    int i0 = use_lds ? EIdx[e] : esrc[lo + e];
                    size_t s0 = (size_t)i0 * KP;
                    bfrag a0 = *(const bfrag*)(hcur + s0 + colA);
                    if (sumB) {
                        bfrag b0 = *(const bfrag*)(hcur + s0 + colB);
                        #pragma unroll
                        for (int q = 0; q < 8; ++q) b[q] += bf2f(b0[q]);
                    }
                    #pragma unroll
                    for (int q = 0; q < 8; ++q) a[q] += bf2f(a0[q]);
                }
            }
            __hip_bfloat16 oa[8], ob[8];
            #pragma unroll
            for (int q = 0; q < 8; ++q) {
                oa[q] = __float2bfloat16(a[q]);
                ob[q] = __float2bfloat16(b[q]);
            }
            *(ushort4*)(Awave + rr * KP + colA)     = *(const ushort4*)&oa[0];
            *(ushort4*)(Awave + rr * KP + colA + 4) = *(const ushort4*)&oa[4];
            if (ck < 12) {   // chunks 16..27 (25..27 are zero pads; b stayed 0)
                *(ushort4*)(Awave + rr * KP + colB)     = *(const ushort4*)&ob[0];
                *(ushort4*)(Awave + rr * KP + colB + 4) = *(const ushort4*)&ob[4];
            }
        }
        // read this phase's A fragments (own-wave LDS region only)
        #pragma unroll
        for (int t = 0; t < 7; ++t)
            av[p][t] = *(const bfrag*)&Awave[mrow * KP + t * 32 + kq * 8];
    }

    // ---- load this wave's H fragments from global (contiguous rows) ----
    size_t hbase = (size_t)(wbase + mrow) * KP + kq * 8;
    #pragma unroll
    for (int mf = 0; mf < 2; ++mf)
        #pragma unroll
        for (int t = 0; t < 7; ++t)
            hv[mf][t] = *(const bfrag*)(hcur + hbase + mf * 16 * KP + t * 32);

    const short* Wstep = g_Wall + (size_t)step * 13 * TILE_SHORTS;
    int jcol = lane & 15;
    int rowq = (lane >> 4) * 4;

    __syncthreads();                       // all frag reads done; LDS -> stage buffers
    stage_third(Wstep, &LDS[0], wave, lane);   // stage 0 = (jt0, gates 0,1)

    facc acc[6][2];
    unsigned short hold_u[2][4];

    int jt = 0, ph = 0;
    for (int ss = 0; ss < 39; ++ss) {
        __syncthreads();   // stage ss DMA complete; buf[(ss+1)&1] free for restage
        if (ss + 1 < 39)
            stage_third(Wstep + (size_t)(ss + 1) * STAGE_SHORTS,
                        &LDS[((ss + 1) & 1) * STAGE_SHORTS], wave, lane);

        int j = jt * 16 + jcol;
        const short* Bcur = &LDS[(ss & 1) * STAGE_SHORTS];

        if (ph == 0) {
            // preload old-h for this jt's epilogue (latency hides under 3 stages)
            #pragma unroll
            for (int mf = 0; mf < 2; ++mf)
                #pragma unroll
                for (int r = 0; r < 4; ++r)
                    hold_u[mf][r] = *(const unsigned short*)
                        (hcur + (size_t)(wbase + mf * 16 + rowq + r) * KP + j);
            #pragma unroll
            for (int g = 0; g < 6; ++g)
                #pragma unroll
                for (int mf = 0; mf < 2; ++mf) acc[g][mf] = (facc)(0.0f);
            // gates 0,1 (gi) consume av
            #pragma unroll
            for (int t = 0; t < 7; ++t) {
                bfrag bv0 = *(const bfrag*)&Bcur[(size_t)(((0 * 7 + t) * 64) + lane) * 8];
                bfrag bv1 = *(const bfrag*)&Bcur[(size_t)(((1 * 7 + t) * 64) + lane) * 8];
                #pragma unroll
                for (int mf = 0; mf < 2; ++mf) {
                    acc[0][mf] = __builtin_amdgcn_mfma_f32_16x16x32_bf16(av[mf][t], bv0, acc[0][mf], 0, 0, 0);
                    acc[1][mf] = __builtin_amdgcn_mfma_f32_16x16x32_bf16(av[mf][t], bv1, acc[1][mf], 0, 0, 0);
                }
            }
            ph = 1;
        } else if (ph == 1) {
            // gate 2 (gi, av) and gate 3 (gh, hv)
            #pragma unroll
            for (int t = 0; t < 7; ++t) {
                bfrag bv0 = *(const bfrag*)&Bcur[(size_t)(((0 * 7 + t) * 64) + lane) * 8];
                bfrag bv1 = *(const bfrag*)&Bcur[(size_t)(((1 * 7 + t) * 64) + lane) * 8];
                #pragma unroll
                for (int mf = 0; mf < 2; ++mf) {
                    acc[2][mf] = __builtin_amdgcn_mfma_f32_16x16x32_bf16(av[mf][t], bv0, acc[2][mf], 0, 0, 0);
                    acc[3][mf] = __builtin_amdgcn_mfma_f32_16x16x32_bf16(hv[mf][t], bv1, acc[3][mf], 0, 0, 0);
                }
            }
            ph = 2;
        } else {
            // gates 4,5 (gh) consume hv
            #pragma unroll
            for (int t = 0; t < 7; ++t) {
                bfrag bv0 = *(const bfrag*)&Bcur[(size_t)(((0 * 7 + t) * 64) + lane) * 8];
                bfrag bv1 = *(const bfrag*)&Bcur[(size_t)(((1 * 7 + t) * 64) + lane) * 8];
                #pragma unroll
                for (int mf = 0; mf < 2; ++mf) {
                    acc[4][mf] = __builtin_amdgcn_mfma_f32_16x16x32_bf16(hv[mf][t], bv0, acc[4][mf], 0, 0, 0);
                    acc[5][mf] = __builtin_amdgcn_mfma_f32_16x16x32_bf16(hv[mf][t], bv1, acc[5][mf], 0, 0, 0);
                }
            }

            // epilogue: C/D layout col=lane&15 (j), row=(lane>>4)*4+reg (m)
            float tmax = 0.0f;
            if (j < D) {
                float bir = g_bias[j],          biz = g_bias[DP + j],     bin = g_bias[2 * DP + j];
                float bhr = g_bias[3 * DP + j], bhz = g_bias[4 * DP + j], bhn = g_bias[5 * DP + j];
                #pragma unroll
                for (int mf = 0; mf < 2; ++mf) {
                    int m0 = wbase + mf * 16 + rowq;
                    #pragma unroll
                    for (int r = 0; r < 4; ++r) {
                        int m = m0 + r;
                        if (m < N_NODES) {
                            float hold = bf2f((short)hold_u[mf][r]);
                            float rr = fast_sigmoid(acc[0][mf][r] + bir + acc[3][mf][r] + bhr);
                            float zz = fast_sigmoid(acc[1][mf][r] + biz + acc[4][mf][r] + bhz);
                            float nn = fast_tanh(acc[2][mf][r] + bin + rr * (acc[5][mf][r] + bhn));
                            float hv2 = (1.0f - zz) * nn + zz * hold;
                            hnext[(size_t)m * KP + j] = __float2bfloat16(hv2);
                            if (hv2 > tmax) tmax = hv2;
                        }
                    }
                }
                if (dopool) atomicMax(&pmax[j], __float_as_uint(tmax));
            }
            ph = 0; ++jt;
        }
    }

    if (dopool) {
        __syncthreads();
        for (int c = tid; c < D; c += 256) atomicMax(&pooled[c], pmax[c]);
    }
}

// ---------------- logits + softmax ----------------
__global__ void head_kernel(const unsigned int* __restrict__ pooled,
                            const float* __restrict__ cls_w,
                            const float* __restrict__ cls_b,
                            float* __restrict__ out) {
    if (threadIdx.x == 0) {
        float l0 = cls_b[0], l1 = cls_b[1];
        for (int d = 0; d < D; ++d) {
            float p = __uint_as_float(pooled[d]);
            l0 += p * cls_w[d];
            l1 += p * cls_w[D + d];
        }
        float mx = l0 > l1 ? l0 : l1;
        float e0 = expf(l0 - mx), e1 = expf(l1 - mx);
        out[0] = e0 / (e0 + e1);
        out[1] = e1 / (e0 + e1);
    }
}

extern "C" void kernel_launch(void* const* d_in, const int* in_sizes, int n_in,
                              void* d_out, int out_size, void* d_ws, size_t ws_size,
                              hipStream_t stream) {
    const float* x     = (const float*)d_in[0];
    const float* W     = (const float*)d_in[1];
    const float* w_ih  = (const float*)d_in[2];
    const float* w_hh  = (const float*)d_in[3];
    const float* b_ih  = (const float*)d_in[4];
    const float* b_hh  = (const float*)d_in[5];
    const float* cls_w = (const float*)d_in[6];
    const float* cls_b = (const float*)d_in[7];
    const int*   ei    = (const int*)d_in[8];
    const int* src = ei;
    const int* dst = ei + N_EDGES;

    const size_t ROWB = (size_t)N_PAD * KP;     // bf16 elements per buffer
    __hip_bfloat16* hA   = (__hip_bfloat16*)d_ws;
    __hip_bfloat16* hB   = hA + ROWB;
    int* cnt    = (int*)(hB + ROWB);
    int* incl   = cnt + N_NODES;
    int* bsum   = incl + N_NODES;
    int* off    = bsum + 128;
    int* cursor = off + N_NODES + 1;
    int* esrc   = cursor + N_NODES;
    unsigned int* pooled = (unsigned int*)(esrc + N_EDGES);

    // CSR build (once per call; edges are step-invariant)
    hipMemsetAsync(cnt, 0, N_NODES * sizeof(int), stream);
    count_kernel<<<(N_EDGES + 255) / 256, 256, 0, stream>>>(dst, cnt);
    scan1<<<(N_NODES + SCAN_B - 1) / SCAN_B, SCAN_B, 0, stream>>>(cnt, incl, bsum);
    scan2<<<1, 128, 0, stream>>>(bsum, (N_NODES + SCAN_B - 1) / SCAN_B);
    scan3<<<(N_NODES + 255) / 256, 256, 0, stream>>>(cnt, incl, bsum, off, cursor);
    fill_kernel<<<(N_EDGES + 255) / 256, 256, 0, stream>>>(src, dst, cursor, esrc);

    // weight prep (wconv blocks 0..545 = fragment permute, 546..550 = bias)
    wc_kernel<<<NUM_STEPS * 600, 256, 0, stream>>>(W, w_ih);
    wconv_kernel<<<551, 256, 0, stream>>>(w_hh, b_ih, b_hh);

    pad_kernel<<<(int)(ROWB / 256), 256, 0, stream>>>(x, hA);
    hipMemsetAsync(pooled, 0, D * sizeof(unsigned int), stream);

    __hip_bfloat16* hcur = hA;
    __hip_bfloat16* hnext = hB;
    for (int s = 0; s < NUM_STEPS; ++s) {
        gru_fused<<<N_PAD / 128, 256, 0, stream>>>(hcur, hnext, off, esrc, pooled, s);
        __hip_bfloat16* t = hcur; hcur = hnext; hnext = t;
    }
    head_kernel<<<1, 64, 0, stream>>>(pooled, cls_w, cls_b, (float*)d_out);
}

// Round 15
// 830.698 us; speedup vs baseline: 2.3138x; 2.3138x over previous
//
#include <hip/hip_runtime.h>
#include <hip/hip_bf16.h>
#include <math.h>

#define N_NODES 100000
#define N_PAD   100096   // multiple of 256
#define N_EDGES 400000
#define IN_DIM  100
#define D       200
#define DP      208      // j padded to 13*16
#define KP      224      // k padded to 7*32
#define NUM_STEPS 4

#define TILE_SHORTS  21504         // full jt tile: 6 gates * 7 kt * 64 lanes * 8 shorts
#define HALF_SHORTS  10752         // 3 gates
#define HALF_GROUPS  21            // 1344 chunks / 64 lanes
#define EIDX_CAP     896           // per-wave LDS edge-index capacity

typedef __attribute__((ext_vector_type(8))) short bfrag;   // 8 bf16 (4 VGPRs)
typedef __attribute__((ext_vector_type(4))) float facc;    // 4 fp32

// weights, per-(step,jt) CONTIGUOUS tile: [s][jt][g6][t7][lane64][8]
__device__ short g_Wall[NUM_STEPS * 13 * TILE_SHORTS];
__device__ float g_bias[6 * DP];

__device__ __forceinline__ float fast_sigmoid(float x) {
    return __builtin_amdgcn_rcpf(1.0f + __expf(-x));
}
__device__ __forceinline__ float fast_tanh(float x) {
    return 2.0f * __builtin_amdgcn_rcpf(1.0f + __expf(-2.0f * x)) - 1.0f;
}
__device__ __forceinline__ float bf2f(short u) {
    unsigned int x = ((unsigned int)(unsigned short)u) << 16;
    return __uint_as_float(x);
}

// ---------------- weight permute + Wc-fold + bias, all in one kernel ----------------
// blocks 0..545: fragment permute. Gates 0-2 fold Wc = w_ih @ W[s]^T inline:
//   Wc[s][g*200+j][k] = sum_t w_ih[g*200+j][t] * W[s][k][t]
// blocks 546+: bias packing.
__global__ __launch_bounds__(256) void wconv_kernel(const float* __restrict__ W,
                                                    const float* __restrict__ w_ih,
                                                    const float* __restrict__ w_hh,
                                                    const float* __restrict__ b_ih,
                                                    const float* __restrict__ b_hh) {
    if (blockIdx.x >= 546) {
        int idx = (blockIdx.x - 546) * 256 + threadIdx.x;
        if (idx < 6 * DP) {
            int g = idx / DP, j = idx % DP;
            float v = 0.0f;
            if (j < D) v = (g < 3) ? b_ih[g * 200 + j] : b_hh[(g - 3) * 200 + j];
            g_bias[idx] = v;
        }
        return;
    }
    int idx = blockIdx.x * 256 + threadIdx.x;   // < 4*13*6*7*64 = 139776
    int l  = idx & 63;
    int t  = (idx >> 6) % 7;
    int g  = (idx / 448) % 6;
    int jt = (idx / 2688) % 13;
    int s  = idx / 34944;
    int j  = jt * 16 + (l & 15);
    int k0 = t * 32 + (l >> 4) * 8;
    short* out = g_Wall + (size_t)idx * 8;
    float vals[8];
    if (g < 3) {
        // fold: vals[i] = dot(w_ih[g*200+j], W[s][k0+i])
        const float* wr = (j < D) ? &w_ih[(size_t)(g * 200 + j) * D] : nullptr;
        #pragma unroll
        for (int i = 0; i < 8; ++i) vals[i] = 0.0f;
        if (wr) {
            #pragma unroll
            for (int i = 0; i < 8; ++i) {
                int k = k0 + i;
                if (k < D) {
                    const float* Wr = &W[(size_t)s * D * D + (size_t)k * D];
                    float acc = 0.0f;
                    #pragma unroll 4
                    for (int tt = 0; tt < D; ++tt) acc += wr[tt] * Wr[tt];
                    vals[i] = acc;
                }
            }
        }
    } else {
        #pragma unroll
        for (int i = 0; i < 8; ++i) {
            int k = k0 + i;
            vals[i] = (j < D && k < D) ? w_hh[((size_t)(g - 3) * 200 + j) * D + k] : 0.0f;
        }
    }
    #pragma unroll
    for (int i = 0; i < 8; ++i) {
        __hip_bfloat16 b = __float2bfloat16(vals[i]);
        out[i] = *reinterpret_cast<short*>(&b);
    }
}

// ---------------- pad: h[:, :100] = bf16(x), rest 0 ----------------
__global__ void pad_kernel(const float* __restrict__ x, __hip_bfloat16* __restrict__ h) {
    int idx = blockIdx.x * 256 + threadIdx.x;   // N_PAD*KP exact multiple of 256
    int n = idx / KP, c = idx % KP;
    float v = (n < N_NODES && c < IN_DIM) ? x[n * IN_DIM + c] : 0.0f;
    h[idx] = __float2bfloat16(v);
}

// ---------------- CSR build ----------------
__global__ void count_kernel(const int* __restrict__ dst, int* __restrict__ cnt) {
    int e = blockIdx.x * blockDim.x + threadIdx.x;
    if (e < N_EDGES) atomicAdd(&cnt[dst[e]], 1);
}

#define SCAN_B 1024
#define NB_SCAN ((N_NODES + SCAN_B - 1) / SCAN_B)   // 98
// 2-barrier block scan: wave shuffle-scan + cross-wave LDS
__global__ __launch_bounds__(SCAN_B) void scan1(const int* __restrict__ cnt,
                                                int* __restrict__ incl, int* __restrict__ bsum) {
    __shared__ int ws[16];
    int i = blockIdx.x * SCAN_B + threadIdx.x;
    int lane = threadIdx.x & 63, wid = threadIdx.x >> 6;
    int v = (i < N_NODES) ? cnt[i] : 0;
    int s = v;
    #pragma unroll
    for (int o = 1; o < 64; o <<= 1) {
        int t = __shfl_up(s, o, 64);
        if (lane >= o) s += t;
    }
    if (lane == 63) ws[wid] = s;
    __syncthreads();
    if (wid == 0) {
        int t = (lane < 16) ? ws[lane] : 0;
        #pragma unroll
        for (int o = 1; o < 16; o <<= 1) {
            int u = __shfl_up(t, o, 64);
            if (lane >= o) t += u;
        }
        if (lane < 16) ws[lane] = t;
    }
    __syncthreads();
    if (wid > 0) s += ws[wid - 1];
    if (i < N_NODES) incl[i] = s;
    if (threadIdx.x == SCAN_B - 1) bsum[blockIdx.x] = s;
}
// scan3 now scans bsum in-LDS itself (scan2 launch eliminated)
__global__ void scan3(const int* __restrict__ cnt, const int* __restrict__ incl,
                      const int* __restrict__ bsum, int* __restrict__ off,
                      int* __restrict__ cursor) {
    __shared__ int sh[128];
    if (threadIdx.x < 128) sh[threadIdx.x] = (threadIdx.x < NB_SCAN) ? bsum[threadIdx.x] : 0;
    __syncthreads();
    for (int o = 1; o < 128; o <<= 1) {
        int t = (threadIdx.x >= o && threadIdx.x < 128) ? sh[threadIdx.x - o] : 0;
        __syncthreads();
        if (threadIdx.x < 128) sh[threadIdx.x] += t;
        __syncthreads();
    }
    int i = blockIdx.x * blockDim.x + threadIdx.x;
    if (i < N_NODES) {
        int b = i / SCAN_B;
        int pre = b ? sh[b - 1] : 0;
        int v = incl[i] - cnt[i] + pre;
        off[i] = v; cursor[i] = v;
    }
    if (i == 0) off[N_NODES] = N_EDGES;
}
__global__ void fill_kernel(const int* __restrict__ src, const int* __restrict__ dst,
                            int* __restrict__ cursor, int* __restrict__ esrc) {
    int e = blockIdx.x * blockDim.x + threadIdx.x;
    if (e < N_EDGES) {
        int pos = atomicAdd(&cursor[dst[e]], 1);
        esrc[pos] = src[e];
    }
}

// ---------------- async stage: one HALF tile (21504 B) global -> LDS ----------------
__device__ __forceinline__ void stage_half(const short* __restrict__ gsrc,
                                           short* lds_dst, int wave, int lane) {
    #pragma unroll
    for (int g = wave; g < HALF_GROUPS; g += 4) {
        __builtin_amdgcn_global_load_lds(
            (const __attribute__((address_space(1))) void*)(gsrc + g * 512 + lane * 8),
            (__attribute__((address_space(3))) void*)(lds_dst + g * 512),
            16, 0, 0);
    }
}

// ---------------- fused gather + MFMA GRU (+ pool on last step) ----------------
// r11 structure (validated best: 163 us/dispatch, 3 blocks/CU).
// NOTE: 3 blocks/CU is register-structural — av/hv (112 VGPR) + acc (48 AGPR)
// ≈160 unified regs -> 3 waves/SIMD; do NOT raise __launch_bounds__ min-waves
// (r14: compiler clamps to 64 VGPR and spills, 2.7x regression).
__global__ __launch_bounds__(256, 2) void gru_fused(const __hip_bfloat16* __restrict__ hcur,
                                                    __hip_bfloat16* __restrict__ hnext,
                                                    const int* __restrict__ off,
                                                    const int* __restrict__ esrc,
                                                    unsigned int* __restrict__ pooled,
                                                    int step) {
    __shared__ short Bs[2][HALF_SHORTS];  // 43008 B; bytes 0..28671 = A-scratch,
                                          // bytes 28672..43007 = edge-index cache
    __shared__ unsigned int pmax[DP];     // step-3 pooling scratch
    int tid = threadIdx.x;
    int lane = tid & 63, wave = tid >> 6;
    int wbase = blockIdx.x * 128 + wave * 32;
    int mrow = lane & 15, kq = lane >> 4;
    bool dopool = (step == NUM_STEPS - 1);

    if (dopool) for (int c = tid; c < DP; c += 256) pmax[c] = 0u;

    short* LDSbase = &Bs[0][0];
    short* Awave = LDSbase + wave * 16 * KP;               // 16 rows x 224 shorts
    int* EIdx = (int*)((char*)LDSbase + 28672) + wave * EIDX_CAP;

    // ---- prefetch this wave's contiguous esrc slice (CSR rows are contiguous) ----
    int nlo = wbase < N_NODES ? wbase : N_NODES;
    int nhi = (wbase + 32) < N_NODES ? (wbase + 32) : N_NODES;
    int lo = off[nlo];
    int cntw = off[nhi] - lo;
    bool use_lds = (cntw <= EIDX_CAP);
    if (use_lds)
        for (int i = lane; i < cntw; i += 64) EIdx[i] = esrc[lo + i];

    bfrag av[2][7], hv[2][7];

    // ---- gather: 2 phases x 16 rows; 4 rows in flight, 4-edge unroll ----
    int r4 = lane >> 4;              // row-in-flight 0..3
    int ck = lane & 15;              // 16B chunk id (this lane also covers ck+16)
    int colA = ck * 8;
    int colB = colA + 128;           // (ck+16)*8
    bool sumB = (ck < 9);            // chunks 16..24 carry data (cols < 200)
    #pragma unroll
    for (int p = 0; p < 2; ++p) {
        #pragma unroll
        for (int it = 0; it < 4; ++it) {
            int rr = it * 4 + r4;            // row within phase
            int n = wbase + p * 16 + rr;
            float a[8] = {0, 0, 0, 0, 0, 0, 0, 0};
            float b[8] = {0, 0, 0, 0, 0, 0, 0, 0};
            if (n < N_NODES) {
                int e0 = off[n] - lo, e1 = off[n + 1] - lo;
                int e = e0;
                for (; e + 3 < e1; e += 4) {
                    int i0, i1, i2, i3;
                    if (use_lds) {
                        i0 = EIdx[e]; i1 = EIdx[e + 1]; i2 = EIdx[e + 2]; i3 = EIdx[e + 3];
                    } else {
                        i0 = esrc[lo + e];     i1 = esrc[lo + e + 1];
                        i2 = esrc[lo + e + 2]; i3 = esrc[lo + e + 3];
                    }
                    size_t s0 = (size_t)i0 * KP, s1 = (size_t)i1 * KP;
                    size_t s2 = (size_t)i2 * KP, s3 = (size_t)i3 * KP;
                    bfrag a0 = *(const bfrag*)(hcur + s0 + colA);
                    bfrag a1 = *(const bfrag*)(hcur + s1 + colA);
                    bfrag a2 = *(const bfrag*)(hcur + s2 + colA);
                    bfrag a3 = *(const bfrag*)(hcur + s3 + colA);
                    if (sumB) {
                        bfrag b0 = *(const bfrag*)(hcur + s0 + colB);
                        bfrag b1 = *(const bfrag*)(hcur + s1 + colB);
                        bfrag b2 = *(const bfrag*)(hcur + s2 + colB);
                        bfrag b3 = *(const bfrag*)(hcur + s3 + colB);
                        #pragma unroll
                        for (int q = 0; q < 8; ++q)
                            b[q] += (bf2f(b0[q]) + bf2f(b1[q])) + (bf2f(b2[q]) + bf2f(b3[q]));
                    }
                    #pragma unroll
                    for (int q = 0; q < 8; ++q)
                        a[q] += (bf2f(a0[q]) + bf2f(a1[q])) + (bf2f(a2[q]) + bf2f(a3[q]));
                }
                for (; e < e1; ++e) {
                    int i0 = use_lds ? EIdx[e] : esrc[lo + e];
                    size_t s0 = (size_t)i0 * KP;
                    bfrag a0 = *(const bfrag*)(hcur + s0 + colA);
                    if (sumB) {
                        bfrag b0 = *(const bfrag*)(hcur + s0 + colB);
                        #pragma unroll
                        for (int q = 0; q < 8; ++q) b[q] += bf2f(b0[q]);
                    }
                    #pragma unroll
                    for (int q = 0; q < 8; ++q) a[q] += bf2f(a0[q]);
                }
            }
            __hip_bfloat16 oa[8], ob[8];
            #pragma unroll
            for (int q = 0; q < 8; ++q) {
                oa[q] = __float2bfloat16(a[q]);
                ob[q] = __float2bfloat16(b[q]);
            }
            *(ushort4*)(Awave + rr * KP + colA)     = *(const ushort4*)&oa[0];
            *(ushort4*)(Awave + rr * KP + colA + 4) = *(const ushort4*)&oa[4];
            if (ck < 12) {   // chunks 16..27 (25..27 are zero pads; b stayed 0)
                *(ushort4*)(Awave + rr * KP + colB)     = *(const ushort4*)&ob[0];
                *(ushort4*)(Awave + rr * KP + colB + 4) = *(const ushort4*)&ob[4];
            }
        }
        // read this phase's A fragments (own-wave LDS region only)
        #pragma unroll
        for (int t = 0; t < 7; ++t)
            av[p][t] = *(const bfrag*)&Awave[mrow * KP + t * 32 + kq * 8];
    }

    // ---- load this wave's H fragments from global (contiguous rows) ----
    size_t hbase = (size_t)(wbase + mrow) * KP + kq * 8;
    #pragma unroll
    for (int mf = 0; mf < 2; ++mf)
        #pragma unroll
        for (int t = 0; t < 7; ++t)
            hv[mf][t] = *(const bfrag*)(hcur + hbase + mf * 16 * KP + t * 32);

    const short* Wstep = g_Wall + (size_t)step * 13 * TILE_SHORTS;
    int jcol = lane & 15;
    int rowq = (lane >> 4) * 4;

    __syncthreads();                       // all frag reads done; LDS -> B buffers
    stage_half(Wstep, &Bs[0][0], wave, lane);   // h0 = (jt0, gi-gates)

    facc acc[6][2];
    unsigned short hold_u[2][4];

    for (int hk = 0; hk < 26; ++hk) {
        __syncthreads();   // h_hk DMA complete; buf[(hk+1)&1] free for restage
        if (hk + 1 < 26)
            stage_half(Wstep + (size_t)(hk + 1) * HALF_SHORTS,
                       &Bs[(hk + 1) & 1][0], wave, lane);

        int jt = hk >> 1;
        int j = jt * 16 + jcol;
        const short* Bcur = &Bs[hk & 1][0];

        if ((hk & 1) == 0) {
            // preload old-h for this jt's epilogue (latency hides under both halves)
            #pragma unroll
            for (int mf = 0; mf < 2; ++mf)
                #pragma unroll
                for (int r = 0; r < 4; ++r)
                    hold_u[mf][r] = *(const unsigned short*)
                        (hcur + (size_t)(wbase + mf * 16 + rowq + r) * KP + j);
            #pragma unroll
            for (int g = 0; g < 6; ++g)
                #pragma unroll
                for (int mf = 0; mf < 2; ++mf) acc[g][mf] = (facc)(0.0f);
            // gi gates (0..2) consume av
            #pragma unroll
            for (int t = 0; t < 7; ++t) {
                bfrag bv[3];
                #pragma unroll
                for (int g = 0; g < 3; ++g)
                    bv[g] = *(const bfrag*)&Bcur[(size_t)(((g * 7 + t) * 64) + lane) * 8];
                #pragma unroll
                for (int g = 0; g < 3; ++g)
                    #pragma unroll
                    for (int mf = 0; mf < 2; ++mf)
                        acc[g][mf] = __builtin_amdgcn_mfma_f32_16x16x32_bf16(av[mf][t], bv[g], acc[g][mf], 0, 0, 0);
            }
        } else {
            // gh gates (3..5) consume hv
            #pragma unroll
            for (int t = 0; t < 7; ++t) {
                bfrag bv[3];
                #pragma unroll
                for (int g = 0; g < 3; ++g)
                    bv[g] = *(const bfrag*)&Bcur[(size_t)(((g * 7 + t) * 64) + lane) * 8];
                #pragma unroll
                for (int g = 0; g < 3; ++g)
                    #pragma unroll
                    for (int mf = 0; mf < 2; ++mf)
                        acc[g + 3][mf] = __builtin_amdgcn_mfma_f32_16x16x32_bf16(hv[mf][t], bv[g], acc[g + 3][mf], 0, 0, 0);
            }

            // epilogue: C/D layout col=lane&15 (j), row=(lane>>4)*4+reg (m)
            float tmax = 0.0f;
            if (j < D) {
                float bir = g_bias[j],          biz = g_bias[DP + j],     bin = g_bias[2 * DP + j];
                float bhr = g_bias[3 * DP + j], bhz = g_bias[4 * DP + j], bhn = g_bias[5 * DP + j];
                #pragma unroll
                for (int mf = 0; mf < 2; ++mf) {
                    int m0 = wbase + mf * 16 + rowq;
                    #pragma unroll
                    for (int r = 0; r < 4; ++r) {
                        int m = m0 + r;
                        if (m < N_NODES) {
                            float hold = bf2f((short)hold_u[mf][r]);
                            float rr = fast_sigmoid(acc[0][mf][r] + bir + acc[3][mf][r] + bhr);
                            float zz = fast_sigmoid(acc[1][mf][r] + biz + acc[4][mf][r] + bhz);
                            float nn = fast_tanh(acc[2][mf][r] + bin + rr * (acc[5][mf][r] + bhn));
                            float hv2 = (1.0f - zz) * nn + zz * hold;
                            hnext[(size_t)m * KP + j] = __float2bfloat16(hv2);
                            if (hv2 > tmax) tmax = hv2;
                        }
                    }
                }
                if (dopool) atomicMax(&pmax[j], __float_as_uint(tmax));
            }
        }
    }

    if (dopool) {
        __syncthreads();
        for (int c = tid; c < D; c += 256) atomicMax(&pooled[c], pmax[c]);
    }
}

// ---------------- logits + softmax ----------------
__global__ void head_kernel(const unsigned int* __restrict__ pooled,
                            const float* __restrict__ cls_w,
                            const float* __restrict__ cls_b,
                            float* __restrict__ out) {
    if (threadIdx.x == 0) {
        float l0 = cls_b[0], l1 = cls_b[1];
        for (int d = 0; d < D; ++d) {
            float p = __uint_as_float(pooled[d]);
            l0 += p * cls_w[d];
            l1 += p * cls_w[D + d];
        }
        float mx = l0 > l1 ? l0 : l1;
        float e0 = expf(l0 - mx), e1 = expf(l1 - mx);
        out[0] = e0 / (e0 + e1);
        out[1] = e1 / (e0 + e1);
    }
}

extern "C" void kernel_launch(void* const* d_in, const int* in_sizes, int n_in,
                              void* d_out, int out_size, void* d_ws, size_t ws_size,
                              hipStream_t stream) {
    const float* x     = (const float*)d_in[0];
    const float* W     = (const float*)d_in[1];
    const float* w_ih  = (const float*)d_in[2];
    const float* w_hh  = (const float*)d_in[3];
    const float* b_ih  = (const float*)d_in[4];
    const float* b_hh  = (const float*)d_in[5];
    const float* cls_w = (const float*)d_in[6];
    const float* cls_b = (const float*)d_in[7];
    const int*   ei    = (const int*)d_in[8];
    const int* src = ei;
    const int* dst = ei + N_EDGES;

    const size_t ROWB = (size_t)N_PAD * KP;     // bf16 elements per buffer
    __hip_bfloat16* hA   = (__hip_bfloat16*)d_ws;
    __hip_bfloat16* hB   = hA + ROWB;
    int* cnt    = (int*)(hB + ROWB);
    int* incl   = cnt + N_NODES;
    int* bsum   = incl + N_NODES;
    int* off    = bsum + 128;
    int* cursor = off + N_NODES + 1;
    int* esrc   = cursor + N_NODES;
    unsigned int* pooled = (unsigned int*)(esrc + N_EDGES);

    // CSR build (once per call; edges are step-invariant)
    hipMemsetAsync(cnt, 0, N_NODES * sizeof(int), stream);
    count_kernel<<<(N_EDGES + 255) / 256, 256, 0, stream>>>(dst, cnt);
    scan1<<<NB_SCAN, SCAN_B, 0, stream>>>(cnt, incl, bsum);
    scan3<<<(N_NODES + 255) / 256, 256, 0, stream>>>(cnt, incl, bsum, off, cursor);
    fill_kernel<<<(N_EDGES + 255) / 256, 256, 0, stream>>>(src, dst, cursor, esrc);

    // weight prep (one kernel: fragment permute + Wc fold + bias)
    wconv_kernel<<<551, 256, 0, stream>>>(W, w_ih, w_hh, b_ih, b_hh);

    pad_kernel<<<(int)(ROWB / 256), 256, 0, stream>>>(x, hA);
    hipMemsetAsync(pooled, 0, D * sizeof(unsigned int), stream);

    __hip_bfloat16* hcur = hA;
    __hip_bfloat16* hnext = hB;
    for (int s = 0; s < NUM_STEPS; ++s) {
        gru_fused<<<N_PAD / 128, 256, 0, stream>>>(hcur, hnext, off, esrc, pooled, s);
        __hip_bfloat16* t = hcur; hcur = hnext; hnext = t;
    }
    head_kernel<<<1, 64, 0, stream>>>(pooled, cls_w, cls_b, (float*)d_out);
}